// Round 8
// baseline (26330.453 us; speedup 1.0000x reference)
//
#include <hip/hip_runtime.h>
#include <cstdint>
#include <cstddef>

typedef __bf16 bf16x8 __attribute__((ext_vector_type(8)));
typedef __bf16 bf16x4 __attribute__((ext_vector_type(4)));
typedef float  f32x4  __attribute__((ext_vector_type(4)));

#define MFMA16(a,b,c) __builtin_amdgcn_mfma_f32_16x16x32_bf16((a),(b),(c),0,0,0)

// LDS-only barrier: per-step h double-buffer handoff needs lgkmcnt(0) only.
// Global stores are drained explicitly at publish points (BAR_FULL).
#define BAR_LGKM() __asm__ volatile("s_waitcnt lgkmcnt(0)\n\ts_barrier" ::: "memory")
#define BAR_FULL() __asm__ volatile("s_waitcnt vmcnt(0) lgkmcnt(0)\n\ts_barrier" ::: "memory")

// Problem: B=256, T=512, D=H=128, 3H=384. out batch stride = 65536 elems.
//
// Structure: conv_x (x fp32 -> bf16, frag-ready [b][t][c] layout), prep_frags
// (weights), then ONE 32-block gru_pipe: blocks 0..15 layer 0 (producer),
// 16..31 layer 1 (consumer, lagged 8+ steps behind via per-pair flags).
// Step inputs (x-bf16 / h0-bf16) are loaded DIRECTLY from global memory as
// MFMA B-frags (no LDS staging; L1 absorbs cross-wave redundancy). LDS holds
// only the per-step h exchange. h0 crosses XCDs as bf16 nt stores/loads.
//
// Transposed MFMA orientation: A = stacked weights (M=gates), B = dynamic
// [x|h] (N=batch). C: col(lane&15)=batch, rows = 4 consecutive gate-cols.

// ---------------------------------------------------------------------------
// conv_x: x [256][512][128] fp32 -> bf16 at (xb, strides). 2048 x 512.
// ---------------------------------------------------------------------------
__global__ __launch_bounds__(512) void conv_x(const float* __restrict__ x,
        char* __restrict__ xb, size_t xsT, size_t xsB)
{
    int id = blockIdx.x * 512 + threadIdx.x;   // 0..1048575, 16 elems each
    int c16 = id & 7;
    int bt  = id >> 3;
    int b = bt >> 9, t = bt & 511;
    const float4* src = (const float4*)(x + (size_t)bt * 128 + c16 * 16);
    float4 v0 = src[0], v1 = src[1], v2 = src[2], v3 = src[3];
    bf16x8 o0, o1;
    o0[0]=(__bf16)v0.x; o0[1]=(__bf16)v0.y; o0[2]=(__bf16)v0.z; o0[3]=(__bf16)v0.w;
    o0[4]=(__bf16)v1.x; o0[5]=(__bf16)v1.y; o0[6]=(__bf16)v1.z; o0[7]=(__bf16)v1.w;
    o1[0]=(__bf16)v2.x; o1[1]=(__bf16)v2.y; o1[2]=(__bf16)v2.z; o1[3]=(__bf16)v2.w;
    o1[4]=(__bf16)v3.x; o1[5]=(__bf16)v3.y; o1[6]=(__bf16)v3.z; o1[7]=(__bf16)v3.w;
    bf16x8* dst = (bf16x8*)(xb + (size_t)b * xsB + (size_t)t * xsT + c16 * 32);
    dst[0] = o0; dst[1] = o1;
}

// ---------------------------------------------------------------------------
// prep_frags: stacked-weight A-frags, K=256 ([W(128);U(128)]), + flag init.
// Elem offset ((ct*8+kt)*64 + lane)*8 + j holds
// Wstack[kt*32 + (lane>>4)*8 + j][ct*16 + (lane&15)]  (ct 0..23, kt 0..7).
// ---------------------------------------------------------------------------
__global__ void prep_frags(const float* __restrict__ W0, const float* __restrict__ U0,
                           const float* __restrict__ W1, const float* __restrict__ U1,
                           __bf16* __restrict__ frags, int* __restrict__ flags)
{
    if (blockIdx.x == 0 && threadIdx.x < 16) flags[threadIdx.x * 16] = 0;
    int id = blockIdx.x * 512 + threadIdx.x;      // 0..24575
    int layer = id / 12288;
    int r     = id % 12288;                       // (ct*8+kt)*64 + lane
    int lane = r & 63;
    int ctkt = r >> 6;                            // 0..191
    int kt = ctkt & 7;
    int ct = ctkt >> 3;
    const float* Wsrc = layer ? W1 : W0;
    const float* Usrc = layer ? U1 : U0;
    int n  = ct * 16 + (lane & 15);
    int k0 = kt * 32 + (lane >> 4) * 8;           // never straddles 128
    const float* src = (k0 < 128) ? (Wsrc + (size_t)k0 * 384)
                                  : (Usrc + (size_t)(k0 - 128) * 384);
    __bf16* dst = frags + (size_t)layer * 98304 + (size_t)r * 8;
#pragma unroll
    for (int j = 0; j < 8; j++)
        dst[j] = (__bf16)src[(size_t)j * 384 + n];
}

// ---------------------------------------------------------------------------
// gru_pipe: both GRU layers, pipelined across block pairs.
// Per block: 16 batch rows, 512 threads (8 waves, 2/SIMD). Wave w owns gate
// cols [16w,16w+16) via A-tiles ct = 8g + w. Lane: batch = B0+l15,
// gate-cols c0..c0+3 (c0 = 16w + 4*quad).
// Step input B-frags loaded directly from global bf16 (prefetch 2 steps,
// 2-deep reg pipeline). LDS: h exchange only (2 x 16 x 136 bf16), ONE lgkm
// barrier/step. acc: z(K256 merged), r(K256 merged), xh(kt0-3), rh(kt4-7).
// Producer: h -> h0bf (nt b64) + flag publish every 8th step after BAR_FULL.
// Consumer: gated nt loads of h0bf; out = fp32 float4.
// Fallback packing (small ws): xbf/h0bf live inside out slots — consumed
// strictly before the trailing consumer overwrites each slot.
// ---------------------------------------------------------------------------
__global__ __launch_bounds__(512, 2) void gru_pipe(
    const __bf16* __restrict__ frags,
    const float* __restrict__ b0, const float* __restrict__ b1,
    char* xb, size_t xsT, size_t xsB,
    char* hb, size_t hsT, size_t hsB,
    float* out, int* flags)
{
    __shared__ __align__(16) __bf16 ab[2][16 * 136];

    const int tid = threadIdx.x;
    const int wave = tid >> 6, lane = tid & 63;
    const int l15 = lane & 15, quad = lane >> 4;
    const int pair  = blockIdx.x & 15;
    const int layer = blockIdx.x >> 4;
    const int B0 = pair * 16;
    int* const flagp = flags + pair * 16;          // one 64B line per pair

    const __bf16* Bf  = frags + (size_t)layer * 98304;
    const float* bias = layer ? b1 : b0;

    // persistent weight A-frags: 3 gates x 8 kt = 24 frags (96 VGPR)
    bf16x8 wfr[3][8];
#pragma unroll
    for (int g = 0; g < 3; g++) {
        int ct = 8 * g + wave;
#pragma unroll
        for (int kt = 0; kt < 8; kt++)
            wfr[g][kt] = *(const bf16x8*)(Bf + (size_t)((ct * 8 + kt) * 64 + lane) * 8);
    }

    const int c0 = wave * 16 + quad * 4;           // 4 gate-cols owned by lane
    const f32x4 bz4  = *(const f32x4*)(bias + c0)       + *(const f32x4*)(bias + 384 + c0);
    const f32x4 br4  = *(const f32x4*)(bias + 128 + c0) + *(const f32x4*)(bias + 512 + c0);
    const f32x4 bih4 = *(const f32x4*)(bias + 256 + c0);
    const f32x4 brh4 = *(const f32x4*)(bias + 640 + c0);

    // per-lane input base: batch B0+l15, col chunk quad*8 (slab kt adds kt*64 B)
    const char* inp = (layer ? hb : xb)
                    + (size_t)(B0 + l15) * (layer ? hsB : xsB) + (size_t)(quad * 8) * 2;
    const size_t isT = layer ? hsT : xsT;

    // producer h0bf store: batch B0+l15, cols c0.. (b64 per step)
    char* const hstore = hb + (size_t)(B0 + l15) * hsB + (size_t)c0 * 2;
    // consumer out store: one float4 per step
    float* const po = out + (size_t)(B0 + l15) * 65536 + c0;

    int known = 0;
    if (layer) {
        known = __hip_atomic_load(flagp, __ATOMIC_RELAXED, __HIP_MEMORY_SCOPE_AGENT);
        while (known < 2) {
            __builtin_amdgcn_s_sleep(4);
            known = __hip_atomic_load(flagp, __ATOMIC_RELAXED, __HIP_MEMORY_SCOPE_AGENT);
        }
    }

    // ---- prologue: prefetch step 0/1 input frags, zero h buffer 0 ----
    bf16x8 xf[2][4];
#pragma unroll
    for (int kt = 0; kt < 4; kt++) {
        const bf16x8* p0 = (const bf16x8*)(inp + 0 * isT + kt * 64);
        const bf16x8* p1 = (const bf16x8*)(inp + 1 * isT + kt * 64);
        if (layer) { xf[0][kt] = __builtin_nontemporal_load(p0);
                     xf[1][kt] = __builtin_nontemporal_load(p1); }
        else       { xf[0][kt] = *p0; xf[1][kt] = *p1; }
    }
    if (tid < 272) ((uint4*)&ab[0][0])[tid] = make_uint4(0, 0, 0, 0);
    __syncthreads();

    f32x4 hold = {0.f, 0.f, 0.f, 0.f};
    const int abase = l15 * 136 + quad * 8;        // h B-frag read base
    const int hwoff = l15 * 136 + c0;              // h b64 write base

    for (int t = 0; t < 512; t++) {
        const int cur = t & 1, nxt = cur ^ 1;

        if (layer) {                                // gate this iter's t+2 loads
            int need = t + 3; if (need > 512) need = 512;
            if (known < need) {
                known = __hip_atomic_load(flagp, __ATOMIC_RELAXED, __HIP_MEMORY_SCOPE_AGENT);
                while (known < need) {
                    __builtin_amdgcn_s_sleep(4);
                    known = __hip_atomic_load(flagp, __ATOMIC_RELAXED, __HIP_MEMORY_SCOPE_AGENT);
                }
            }
        }

        // h-part B-frags from LDS (slabs kt=4..7)
        bf16x8 hA[4];
#pragma unroll
        for (int kt = 0; kt < 4; kt++)
            hA[kt] = *(const bf16x8*)&ab[cur][abase + kt * 32];

        f32x4 acc[4] = {{0,0,0,0},{0,0,0,0},{0,0,0,0},{0,0,0,0}};
#pragma unroll
        for (int kt = 0; kt < 4; kt++) {           // x/h0 part (regs, K 0..127)
            acc[0] = MFMA16(wfr[0][kt], xf[cur][kt], acc[0]);
            acc[1] = MFMA16(wfr[1][kt], xf[cur][kt], acc[1]);
            acc[2] = MFMA16(wfr[2][kt], xf[cur][kt], acc[2]);
        }
#pragma unroll
        for (int kt = 0; kt < 4; kt++) {           // h part (LDS, K 128..255)
            acc[0] = MFMA16(wfr[0][kt + 4], hA[kt], acc[0]);
            acc[1] = MFMA16(wfr[1][kt + 4], hA[kt], acc[1]);
            acc[3] = MFMA16(wfr[2][kt + 4], hA[kt], acc[3]);
        }

        f32x4 hnew;
#pragma unroll
        for (int r = 0; r < 4; r++) {
            float zp = acc[0][r] + bz4[r];
            float rp = acc[1][r] + br4[r];
            float z  = __builtin_amdgcn_rcpf(1.f + __expf(-zp));
            float rg = __builtin_amdgcn_rcpf(1.f + __expf(-rp));
            float hp = (acc[2][r] + bih4[r]) + rg * (acc[3][r] + brh4[r]);
            float e2 = __expf(2.f * hp);
            float th = 1.f - 2.f * __builtin_amdgcn_rcpf(e2 + 1.f);
            hnew[r] = th + z * (hold[r] - th);
            hold[r] = hnew[r];
        }

        // h_t -> LDS (next buffer): one b64 write
        {
            bf16x4 hv;
            hv.x = (__bf16)hnew[0]; hv.y = (__bf16)hnew[1];
            hv.z = (__bf16)hnew[2]; hv.w = (__bf16)hnew[3];
            *(bf16x4*)&ab[nxt][hwoff] = hv;
        }

        // barrier: lgkm-only normally; full drain + publish every 8th step.
        // (BAR_FULL drains producer nt-stores of steps <= t-1 -> flag = t.)
        if (layer == 0 && (t & 7) == 7) {
            BAR_FULL();
            if (tid == 0)
                __hip_atomic_store(flagp, t, __ATOMIC_RELAXED,
                                   __HIP_MEMORY_SCOPE_AGENT);
        } else {
            BAR_LGKM();
        }

        // prefetch input frags for t+2 (after barrier: decoupled from drains)
        {
            const size_t t2 = (t < 510) ? (size_t)(t + 2) : 511;
#pragma unroll
            for (int kt = 0; kt < 4; kt++) {
                const bf16x8* p = (const bf16x8*)(inp + t2 * isT + kt * 64);
                xf[cur][kt] = layer ? __builtin_nontemporal_load(p) : *p;
            }
        }

        // h_t -> global (drains during later steps)
        if (layer == 0) {
            bf16x4 hv;
            hv.x = (__bf16)hnew[0]; hv.y = (__bf16)hnew[1];
            hv.z = (__bf16)hnew[2]; hv.w = (__bf16)hnew[3];
            __builtin_nontemporal_store(hv, (bf16x4*)(hstore + (size_t)t * hsT));
        } else {
            *(f32x4*)(po + (size_t)t * 128) = hnew;
        }
    }

    if (layer == 0) {
        BAR_FULL();        // drain final h0bf stores (incl. step 511)
        if (tid == 0)
            __hip_atomic_store(flagp, 512, __ATOMIC_RELAXED,
                               __HIP_MEMORY_SCOPE_AGENT);
    }
}

// ---------------------------------------------------------------------------
extern "C" void kernel_launch(void* const* d_in, const int* in_sizes, int n_in,
                              void* d_out, int out_size, void* d_ws, size_t ws_size,
                              hipStream_t stream)
{
    const float* x  = (const float*)d_in[0];
    const float* W0 = (const float*)d_in[1];
    const float* U0 = (const float*)d_in[2];
    const float* b0 = (const float*)d_in[3];
    const float* W1 = (const float*)d_in[4];
    const float* U1 = (const float*)d_in[5];
    const float* b1 = (const float*)d_in[6];
    float* out = (float*)d_out;

    char* ws = (char*)d_ws;
    __bf16* frags = (__bf16*)ws;                 // 2 * 98304 bf16 = 393,216 B
    int*    flags = (int*)(ws + 393216);         // 16 pairs x 64 B

    // xbf / h0bf placement: ws if it fits, else packed inside out slots:
    // slot (b,t) = 512 B at out + b*262144 + t*512; xbf in [0,256),
    // h0bf in [256,512). Producer/consumer consume (b,t) data strictly
    // before the trailing consumer's full fp32 overwrite of slot (b,t).
    char *xbase, *hbase;
    size_t xsT, xsB, hsT, hsB;
    const size_t need = 458752 + 2 * 33554432;   // frags/flags + xbf + h0bf
    if (ws_size >= need) {
        xbase = ws + 458752;             xsT = 256; xsB = 131072;
        hbase = ws + 458752 + 33554432;  hsT = 256; hsB = 131072;
    } else {
        xbase = (char*)out;              xsT = 512; xsB = 262144;
        hbase = (char*)out + 256;        hsT = 512; hsB = 262144;
    }

    conv_x<<<2048, 512, 0, stream>>>(x, xbase, xsT, xsB);
    prep_frags<<<48, 512, 0, stream>>>(W0, U0, W1, U1, frags, flags);
    gru_pipe<<<32, 512, 0, stream>>>(frags, b0, b1,
                                     xbase, xsT, xsB, hbase, hsT, hsB,
                                     out, flags);
}